// Round 1
// baseline (346.701 us; speedup 1.0000x reference)
//
#include <hip/hip_runtime.h>
#include <hip/hip_bf16.h>

// Problem constants
#define NN 16
#define CF 768
#define CC 64
#define HH 56
#define WW 56
#define SS 40
#define PP (SS*SS)          // 1600 positions per image
#define PPAD 1664           // padded to 13*128
#define NPT (NN*PP)         // 25600
#define NPTP (NN*PPAD)      // 26624
#define HWP (HH*WW)         // 3136

typedef __attribute__((ext_vector_type(8))) short short8;
typedef __attribute__((ext_vector_type(4))) float f32x4;

typedef const __attribute__((address_space(1))) void* gas_p;
typedef __attribute__((address_space(3))) void* las_p;

// Shared bilinear helper — EXACT same arithmetic as validated round-1 kernel.
__device__ __forceinline__ void bilin(float gx, float gy,
    int& o00, int& o01, int& o10, int& o11,
    float& w00, float& w01, float& w10, float& w11)
{
    float x = (gx + 1.f) * 0.5f * (float)(WW - 1);
    float y = (gy + 1.f) * 0.5f * (float)(HH - 1);
    x = fminf(fmaxf(x, 0.f), (float)(WW - 1));
    y = fminf(fmaxf(y, 0.f), (float)(HH - 1));
    float xf = floorf(x), yf = floorf(y);
    int x0 = (int)xf, y0 = (int)yf;
    int x1 = min(x0 + 1, WW - 1), y1 = min(y0 + 1, HH - 1);
    float wx = x - xf, wy = y - yf;
    w00 = (1.f-wx)*(1.f-wy); w01 = wx*(1.f-wy); w10 = (1.f-wx)*wy; w11 = wx*wy;
    o00 = y0*WW + x0; o01 = y0*WW + x1; o10 = y1*WW + x0; o11 = y1*WW + x1;
}

// ---------------------------------------------------------------------------
// Kernel 1: sampling — VERBATIM round-15 kernel (validated).
// ---------------------------------------------------------------------------
__global__ __launch_bounds__(256) void k_sample(
    const float* __restrict__ f0, const float* __restrict__ f1,
    const float* __restrict__ c0in, const float* __restrict__ c1in,
    const float* __restrict__ g0, const float* __restrict__ g1,
    float* __restrict__ nrmF, float* __restrict__ nrmC,
    short* __restrict__ OF0, short* __restrict__ OF1,
    short* __restrict__ OC0, short* __restrict__ OC1)
{
    // decode quarter-interleaved flat index
    const int flat = blockIdx.x;                       // [0, 3328)
    const int q    = (flat >> 3) & 3;                  // quarter
    const int u    = ((flat >> 5) << 3) | (flat & 7);  // [0, 832)
    const int set  = u / 416;                          // 26*16 = 416
    const int rem  = u % 416;
    const int n    = rem / 26;
    const int v    = rem % 26;                         // 0..23 feats, 24..25 code
    const bool isF = v < 24;
    const int ks   = isF ? v : v - 24;
    const int g    = ks * 4 + q;                       // 8-channel group index

    const float* src0; float* nrm; short* out; int NKS;
    if (isF) {
        src0 = (set ? f1 : f0) + ((size_t)n * CF + g * 8) * HWP;
        nrm  = nrmF + (size_t)set * NPTP;
        out  = set ? OF1 : OF0;
        NKS  = 24;
    } else {
        src0 = (set ? c1in : c0in) + ((size_t)n * CC + g * 8) * HWP;
        nrm  = nrmC + (size_t)set * NPTP;
        out  = set ? OC1 : OC0;
        NKS  = 2;
    }
    const float* gr = set ? g1 : g0;
    const int t = threadIdx.x;
    __shared__ float plane[4 * HWP];   // 50 KB
    float keep[7][4];

    // [n][ks][p][32] layout: base of this block's quarter
    const size_t obase = ((size_t)(n * NKS + ks)) * PPAD * 32 + q * 8;

    #pragma unroll
    for (int h = 0; h < 2; h++) {
        if (h) __syncthreads();                 // phase-0 compute done
        const float4* s4 = (const float4*)(src0 + (size_t)h * 4 * HWP);
        #pragma unroll
        for (int i = 0; i < 13; i++) {
            int j = t + i * 256;
            if (j < HWP) ((float4*)plane)[j] = s4[j];
        }
        __syncthreads();

        #pragma unroll
        for (int i = 0; i < 7; i++) {
            int p = t + i * 256;
            if (p >= PPAD) continue;
            if (p < PP) {
                int pg = n * PP + p;
                float2 gg = *(const float2*)&gr[2 * pg];
                int o00, o01, o10, o11; float w00, w01, w10, w11;
                bilin(gg.x*2.f - 1.f, gg.y*2.f - 1.f, o00, o01, o10, o11, w00, w01, w10, w11);
                float v4[4];
                #pragma unroll
                for (int k = 0; k < 4; k++) {
                    const float* pl = plane + k * HWP;
                    v4[k] = w00*pl[o00] + w01*pl[o01] + w10*pl[o10] + w11*pl[o11];
                }
                if (h == 0) {
                    #pragma unroll
                    for (int k = 0; k < 4; k++) keep[i][k] = v4[k];
                } else {
                    float ss = 0.f;
                    short ov[8] __attribute__((aligned(16)));
                    #pragma unroll
                    for (int k = 0; k < 4; k++) {
                        ss += keep[i][k]*keep[i][k] + v4[k]*v4[k];
                        __hip_bfloat16 b0 = __float2bfloat16(keep[i][k]);
                        __hip_bfloat16 b1 = __float2bfloat16(v4[k]);
                        ov[k]     = *(short*)&b0;
                        ov[4 + k] = *(short*)&b1;
                    }
                    *(short8*)&out[obase + (size_t)p * 32] = *(const short8*)ov;
                    atomicAdd(&nrm[n * PPAD + p], ss);
                }
            } else if (h == 1) {
                short8 z = {0,0,0,0,0,0,0,0};
                *(short8*)&out[obase + (size_t)p * 32] = z;
            }
        }
    }
}

// ---------------------------------------------------------------------------
// Kernel 2: nrm -> scale (validated round 10). Pad rows -> scale 0.
// ---------------------------------------------------------------------------
__global__ __launch_bounds__(256) void k_nrm(
    const float* __restrict__ nrmF, const float* __restrict__ nrmC,
    float* __restrict__ sclF, float* __restrict__ sclC)
{
    const int i = blockIdx.x * 256 + threadIdx.x;    // [0, 2*NPTP)
    if (i >= 2 * NPTP) return;
    const float* nrm = blockIdx.y ? nrmC : nrmF;
    float*       scl = blockIdx.y ? sclC : sclF;
    const int p = i % PPAD;
    float s = (p < PP) ? 1.f / fmaxf(sqrtf(nrm[i]), 1e-10f) : 0.f;
    scl[i] = s;
}

// ---------------------------------------------------------------------------
// Kernel 3: fused dual correlation GEMM — round 16: 256x128 block tile,
// 4 waves each owning 128x64 (8x4 fragments, 32 MFMA / 12 ds_read_b128 per
// BK=32 step = +33% LDS intensity vs 64x64 waves). Same proven 3-buffer
// counted-vmcnt(6) pipeline, XOR bank swizzle, XCD-chunked blockIdx swizzle.
// M padded 1664->1792 by clamping staged rows to 1663 (zero-filled pad rows),
// cd (K=64) computed in the EPILOGUE from restaged LDS to avoid the 64-VGPR
// pcd array (keeps total VGPR under 256 for 2 waves/SIMD).
// ---------------------------------------------------------------------------
__global__ __launch_bounds__(256, 2) void k_corr(
    const short* __restrict__ A, const short* __restrict__ B,
    const short* __restrict__ C, const short* __restrict__ D,
    const float* __restrict__ sF, const float* __restrict__ sC,
    float* __restrict__ rowfd, float* __restrict__ rowrc, float* __restrict__ t1out)
{
    // XCD-chunked swizzle: 1456 blocks = 8 XCDs x 182 (bijective)
    const int flat = blockIdx.x;
    const int v   = (flat & 7) * 182 + (flat >> 3);
    const int n   = v / 91;                 // 7 M-tiles x 13 N-tiles per n
    const int rr  = v - n * 91;
    const int bp1 = (rr / 13) * 256;        // M tile base (up to 1536; rows clamp)
    const int bp2 = (rr % 13) * 128;        // N tile base (exact)

    __shared__ short As[3][8192];   // 3 x 16KB (256 rows x 32 k)
    __shared__ short Bs[3][4096];   // 3 x 8KB  (128 rows x 32 k)
    __shared__ float t1s[4];

    const int t    = threadIdx.x;
    const int wv   = t >> 6, lane = t & 63;
    const int wm   = wv >> 1, wn = wv & 1;
    const int frow = lane & 15, fcg = lane >> 4;     // fragment row / k-chunk
    const int fslot = fcg ^ ((frow >> 1) & 3);       // bank-swizzled slot

    // staging geometry: A 4 chunks/thread (1024 chunks), B 2 chunks (512)
    size_t toA[4]; int ldA[4];
    #pragma unroll
    for (int j = 0; j < 4; j++) {
        int g   = wv * 256 + j * 64 + lane;
        int row = g >> 2;
        int cg  = (g & 3) ^ ((row >> 1) & 3);
        toA[j]  = (size_t)min(bp1 + row, PPAD - 1) * 32 + cg * 8;  // clamp: pad rows are zeros
        ldA[j]  = (wv * 4 + j) * 512;      // shorts; wave-uniform base (HW adds lane*16B)
    }
    size_t toB[2]; int ldB[2];
    #pragma unroll
    for (int j = 0; j < 2; j++) {
        int g   = wv * 128 + j * 64 + lane;
        int row = g >> 2;
        int cg  = (g & 3) ^ ((row >> 1) & 3);
        toB[j]  = (size_t)(bp2 + row) * 32 + cg * 8;
        ldB[j]  = (wv * 2 + j) * 512;
    }

    const size_t kstep = (size_t)PPAD * 32;          // shorts per BK=32 step
    const short* fdA = A + (size_t)n * 24 * kstep;
    const short* fdB = B + (size_t)n * 24 * kstep;
    const short* cdC = C + (size_t)n * 2 * kstep;
    const short* cdD = D + (size_t)n * 2 * kstep;

    auto* As3 = (__attribute__((address_space(3))) short*)&As[0][0];
    auto* Bs3 = (__attribute__((address_space(3))) short*)&Bs[0][0];

#define STAGE(PA, PB, OFF, BUF)                                                     \
    do {                                                                            \
        const size_t off_ = (OFF);                                                  \
        _Pragma("unroll")                                                           \
        for (int j_ = 0; j_ < 4; j_++)                                              \
            __builtin_amdgcn_global_load_lds((gas_p)((PA) + toA[j_] + off_),        \
                (las_p)(As3 + (BUF) * 8192 + ldA[j_]), 16, 0, 0);                   \
        _Pragma("unroll")                                                           \
        for (int j_ = 0; j_ < 2; j_++)                                              \
            __builtin_amdgcn_global_load_lds((gas_p)((PB) + toB[j_] + off_),        \
                (las_p)(Bs3 + (BUF) * 4096 + ldB[j_]), 16, 0, 0);                   \
    } while (0)

#define COMPUTE(BUF, ACC)                                                           \
    do {                                                                            \
        short8 bf[4];                                                               \
        _Pragma("unroll")                                                           \
        for (int q = 0; q < 4; q++)                                                 \
            bf[q] = *(const short8*)&Bs[BUF][(wn*64 + q*16 + frow)*32 + fslot*8];   \
        _Pragma("unroll")                                                           \
        for (int m = 0; m < 8; m++) {                                               \
            short8 af = *(const short8*)&As[BUF][(wm*128 + m*16 + frow)*32 + fslot*8]; \
            _Pragma("unroll")                                                       \
            for (int q = 0; q < 4; q++)                                             \
                ACC[m][q] = __builtin_amdgcn_mfma_f32_16x16x32_bf16(af, bf[q], ACC[m][q], 0, 0, 0); \
        }                                                                           \
    } while (0)

#define WAITV6  do { asm volatile("s_waitcnt vmcnt(6)" ::: "memory");               \
                     __builtin_amdgcn_sched_barrier(0);                             \
                     __builtin_amdgcn_s_barrier(); } while (0)
#define WAITV0  do { asm volatile("s_waitcnt vmcnt(0)" ::: "memory");               \
                     __builtin_amdgcn_sched_barrier(0);                             \
                     __builtin_amdgcn_s_barrier(); } while (0)

    // ---- fd main loop: 24 BK=32 steps, step s -> buf s%3 ----
    f32x4 accfd[8][4];
    #pragma unroll
    for (int m = 0; m < 8; m++)
        #pragma unroll
        for (int q = 0; q < 4; q++)
            #pragma unroll
            for (int r = 0; r < 4; r++) accfd[m][q][r] = 0.f;

    STAGE(fdA, fdB, 0, 0);
    STAGE(fdA, fdB, kstep, 1);

    for (int kp = 0; kp < 8; kp++) {
        const size_t tb = (size_t)(3 * kp) * kstep;
        // slot 0: compute step 3kp (buf0), stage step 3kp+2 -> buf2
        WAITV6;
        STAGE(fdA, fdB, tb + 2 * kstep, 2);
        COMPUTE(0, accfd);
        // slot 1: compute step 3kp+1 (buf1), stage 3kp+3 -> buf0
        WAITV6;
        if (kp < 7) STAGE(fdA, fdB, tb + 3 * kstep, 0);
        COMPUTE(1, accfd);
        // slot 2: compute step 3kp+2 (buf2), stage 3kp+4 -> buf1
        if (kp < 7) {
            WAITV6;
            STAGE(fdA, fdB, tb + 4 * kstep, 1);
        } else {
            WAITV0;
        }
        COMPUTE(2, accfd);
    }

    // ---- cd (K=64) staged into freed buffers, computed in epilogue ----
    __syncthreads();
    STAGE(cdC, cdD, 0, 0);
    STAGE(cdC, cdD, kstep, 1);
    asm volatile("s_waitcnt vmcnt(0)" ::: "memory");
    __builtin_amdgcn_sched_barrier(0);
    __builtin_amdgcn_s_barrier();
#undef STAGE
#undef WAITV6
#undef WAITV0

    short8 bc0[4], bc1[4];
    #pragma unroll
    for (int q = 0; q < 4; q++) {
        bc0[q] = *(const short8*)&Bs[0][(wn*64 + q*16 + frow)*32 + fslot*8];
        bc1[q] = *(const short8*)&Bs[1][(wn*64 + q*16 + frow)*32 + fslot*8];
    }
    float sfc_[4], scc_[4];
    #pragma unroll
    for (int q = 0; q < 4; q++) {
        size_t colp = (size_t)NPTP + (size_t)n * PPAD + bp2 + wn*64 + q*16 + frow;
        scc_[q] = sC[colp];
        sfc_[q] = sF[colp];
    }

    // C/D layout: col = lane&15, row = (lane>>4)*4 + reg
    float t1 = 0.f;
    #pragma unroll
    for (int m = 0; m < 8; m++) {
        f32x4 a2[4];
        #pragma unroll
        for (int q = 0; q < 4; q++)
            #pragma unroll
            for (int r = 0; r < 4; r++) a2[q][r] = 0.f;
        short8 ac0 = *(const short8*)&As[0][(wm*128 + m*16 + frow)*32 + fslot*8];
        short8 ac1 = *(const short8*)&As[1][(wm*128 + m*16 + frow)*32 + fslot*8];
        #pragma unroll
        for (int q = 0; q < 4; q++) {
            a2[q] = __builtin_amdgcn_mfma_f32_16x16x32_bf16(ac0, bc0[q], a2[q], 0, 0, 0);
            a2[q] = __builtin_amdgcn_mfma_f32_16x16x32_bf16(ac1, bc1[q], a2[q], 0, 0, 0);
        }
        #pragma unroll
        for (int r = 0; r < 4; r++) {
            int row  = bp1 + wm*128 + m*16 + fcg*4 + r;
            int rowc = min(row, PPAD - 1);            // clamped rows have acc==0 anyway
            float scr = sC[n * PPAD + rowc];
            float sfr = sF[n * PPAD + rowc];
            float sf = 0.f, sr = 0.f;
            #pragma unroll
            for (int q = 0; q < 4; q++) {
                float fdv = accfd[m][q][r] * sfr * sfc_[q];
                float rcv = fmaxf(a2[q][r], 0.f) * scr * scc_[q];
                t1 += rcv * fdv;
                sf += fdv;
                sr += rcv;
            }
            #pragma unroll
            for (int d = 1; d < 16; d <<= 1) {
                sf += __shfl_xor(sf, d, 64);
                sr += __shfl_xor(sr, d, 64);
            }
            if ((lane & 15) == 0 && row < PPAD) {
                atomicAdd(&rowfd[n * PPAD + row], sf);
                atomicAdd(&rowrc[n * PPAD + row], sr);
            }
        }
    }
#undef COMPUTE
    #pragma unroll
    for (int d = 1; d < 64; d <<= 1) t1 += __shfl_xor(t1, d, 64);
    if (lane == 0) t1s[wv] = t1;
    __syncthreads();
    if (t == 0) atomicAdd(t1out, t1s[0] + t1s[1] + t1s[2] + t1s[3]);
}

// ---------------------------------------------------------------------------
// Kernel 4: finalize. loss = -(T1 - cross/PP + (Sfd/M)*Src)/M
// ---------------------------------------------------------------------------
__global__ __launch_bounds__(256) void k_final(
    const float* __restrict__ rowfd, const float* __restrict__ rowrc,
    const float* __restrict__ t1p, float* __restrict__ out)
{
    const int t = threadIdx.x;
    double cr = 0.0, sf = 0.0, sr = 0.0;
    for (int i = t; i < NN * PPAD; i += 256) {
        double a = rowfd[i], b = rowrc[i];
        cr += a * b; sf += a; sr += b;
    }
    __shared__ double sh[256];
    sh[t] = cr; __syncthreads();
    for (int s = 128; s > 0; s >>= 1) { if (t < s) sh[t] += sh[t + s]; __syncthreads(); }
    cr = sh[0]; __syncthreads();
    sh[t] = sf; __syncthreads();
    for (int s = 128; s > 0; s >>= 1) { if (t < s) sh[t] += sh[t + s]; __syncthreads(); }
    sf = sh[0]; __syncthreads();
    sh[t] = sr; __syncthreads();
    for (int s = 128; s > 0; s >>= 1) { if (t < s) sh[t] += sh[t + s]; __syncthreads(); }
    sr = sh[0];
    if (t == 0) {
        double M = (double)NN * (double)PP * (double)PP;
        double t1 = (double)t1p[0];
        double bracket = t1 - cr / (double)PP + (sf / M) * sr;
        out[0] = (float)(-bracket / M);
    }
}

// ---------------------------------------------------------------------------
extern "C" void kernel_launch(void* const* d_in, const int* in_sizes, int n_in,
                              void* d_out, int out_size, void* d_ws, size_t ws_size,
                              hipStream_t stream)
{
    const float* orig_feats     = (const float*)d_in[0];
    const float* orig_feats_pos = (const float*)d_in[1];
    const float* orig_code      = (const float*)d_in[2];
    const float* orig_code_pos  = (const float*)d_in[3];
    const float* coords1        = (const float*)d_in[4];
    const float* coords2        = (const float*)d_in[5];

    // ---- workspace layout (total 89,669,888 B) ----
    char* ws = (char*)d_ws;
    float* t1    = (float*)(ws + 0);                      //      256 B
    float* rowfd = (float*)(ws + 256);                    //  106,496 B (NN*PPAD)
    float* rowrc = (float*)(ws + 106752);                 //  106,496 B
    float* nrmF  = (float*)(ws + 213248);                 //  212,992 B (2*NPTP)
    float* nrmC  = (float*)(ws + 426240);                 //  212,992 B
    const size_t zeroBytes = 639232;                      // t1+rowsums+nrms
    float* sclF  = (float*)(ws + 639232);                 //  212,992 B
    float* sclC  = (float*)(ws + 852224);                 //  212,992 B
    short* OF0 = (short*)(ws + 1065216);                  // [16][24][1664][32] bf16
    short* OF1 = (short*)(ws + 1065216 + 40894464ull);
    short* OC0 = (short*)(ws + 1065216 + 2*40894464ull);  // [16][2][1664][32] bf16
    short* OC1 = (short*)(ws + 1065216 + 2*40894464ull + 3407872ull);

    (void)hipMemsetAsync(d_ws, 0, zeroBytes, stream);   // t1/rowsums/nrms

    k_sample<<<dim3(3328), 256, 0, stream>>>(
        orig_feats, orig_feats_pos, orig_code, orig_code_pos,
        coords1, coords2, nrmF, nrmC, OF0, OF1, OC0, OC1);

    k_nrm<<<dim3((2*NPTP + 255)/256, 2), 256, 0, stream>>>(
        nrmF, nrmC, sclF, sclC);

    k_corr<<<dim3(1456), 256, 0, stream>>>(
        OF0, OF1, OC0, OC1, sclF, sclC, rowfd, rowrc, t1);

    k_final<<<1, 256, 0, stream>>>(rowfd, rowrc, t1, (float*)d_out);
}